// Round 1
// baseline (152.030 us; speedup 1.0000x reference)
//
#include <hip/hip_runtime.h>

// Problem constants (from reference)
#define NQ    10
#define DIM   1024        // 2^NQ
#define N_CLS 10
#define NROWS 16384
#define IMG   784

#define ROWS_PER_BLK 8    // 2048 blocks x 1 wave

// ---------------------------------------------------------------------------
// Wave64 sum via DPP (classic GCN sequence). Result valid in lane 63.
// Runs entirely on the VALU pipe (no LDS / ds_bpermute traffic).
// update_dpp(old=0, bound_ctrl=1): invalid/masked lanes contribute 0.
// ---------------------------------------------------------------------------
__device__ __forceinline__ float wave64_sum(float x) {
#define DPP_ADD(ctrl, rmask, bmask)                                           \
  x += __int_as_float(__builtin_amdgcn_update_dpp(                            \
      0, __float_as_int(x), ctrl, rmask, bmask, true));
  DPP_ADD(0x111, 0xf, 0xf)  // row_shr:1
  DPP_ADD(0x112, 0xf, 0xf)  // row_shr:2
  DPP_ADD(0x114, 0xf, 0xe)  // row_shr:4
  DPP_ADD(0x118, 0xf, 0xc)  // row_shr:8
  DPP_ADD(0x142, 0xa, 0xf)  // row_bcast:15
  DPP_ADD(0x143, 0xc, 0xf)  // row_bcast:31
#undef DPP_ADD
  return x;  // total in lane 63
}

// ---------------------------------------------------------------------------
// Kernel 1: ref[c][d] = canon[c][d] / ||canon[c]|| for d<784, else 0.
// One block per class.
// ---------------------------------------------------------------------------
__global__ void ref_prep_kernel(const float* __restrict__ canon,
                                float* __restrict__ ref) {
  __shared__ float red[256];
  const int c = blockIdx.x;
  const int t = threadIdx.x;
  const float* src = canon + c * IMG;

  float ss = 0.f;
  for (int d = t; d < IMG; d += 256) {
    float v = src[d];
    ss += v * v;
  }
  red[t] = ss;
  __syncthreads();
  for (int s = 128; s > 0; s >>= 1) {
    if (t < s) red[t] += red[t + s];
    __syncthreads();
  }
  const float inv = 1.0f / sqrtf(red[0]);

  for (int d = t; d < DIM; d += 256) {
    ref[c * DIM + d] = (d < IMG) ? src[d] * inv : 0.f;
  }
}

// ---------------------------------------------------------------------------
// Kernel 2: one wave per block; lane i owns columns {256k + 4i .. +3}, k=0..3.
// Per-lane ref fragment (40 x float4 = 160 VGPRs) loaded once, amortized over
// ROWS_PER_BLK rows. z loads are perfectly coalesced dwordx4 (1 KiB/wave-inst).
// ---------------------------------------------------------------------------
__global__ __launch_bounds__(64, 2) void swaptest_kernel(
    const float* __restrict__ zre, const float* __restrict__ zim,
    const float* __restrict__ ref, float* __restrict__ out) {
  const int lane = threadIdx.x;

  // ref fragments: refv[k][c] = ref[c][256k + 4*lane .. +3]
  float4 refv[4][N_CLS];
#pragma unroll
  for (int k = 0; k < 4; ++k) {
#pragma unroll
    for (int c = 0; c < N_CLS; ++c) {
      refv[k][c] =
          *(const float4*)(ref + c * DIM + k * 256 + lane * 4);
    }
  }

  const int row0 = blockIdx.x * ROWS_PER_BLK;

  for (int r = 0; r < ROWS_PER_BLK; ++r) {
    const int row = row0 + r;
    if (row >= NROWS) break;

    const float4* pre = (const float4*)(zre + (size_t)row * DIM);
    const float4* pim = (const float4*)(zim + (size_t)row * DIM);

    float4 zr[4], zi[4];
#pragma unroll
    for (int k = 0; k < 4; ++k) {
      zr[k] = pre[k * 64 + lane];
      zi[k] = pim[k * 64 + lane];
    }

    float are[N_CLS], aim[N_CLS];
#pragma unroll
    for (int c = 0; c < N_CLS; ++c) {
      are[c] = 0.f;
      aim[c] = 0.f;
    }

#pragma unroll
    for (int k = 0; k < 4; ++k) {
#pragma unroll
      for (int c = 0; c < N_CLS; ++c) {
        const float4 rv = refv[k][c];
        are[c] += zr[k].x * rv.x + zr[k].y * rv.y + zr[k].z * rv.z +
                  zr[k].w * rv.w;
        aim[c] += zi[k].x * rv.x + zi[k].y * rv.y + zi[k].z * rv.z +
                  zi[k].w * rv.w;
      }
    }

    // 64-lane reduction on the VALU pipe; totals land in lane 63.
#pragma unroll
    for (int c = 0; c < N_CLS; ++c) {
      are[c] = wave64_sum(are[c]);
      aim[c] = wave64_sum(aim[c]);
    }

    if (lane == 63) {
#pragma unroll
      for (int c = 0; c < N_CLS; ++c) {
        out[(size_t)row * N_CLS + c] = are[c] * are[c] + aim[c] * aim[c];
      }
    }
  }
}

// ---------------------------------------------------------------------------
extern "C" void kernel_launch(void* const* d_in, const int* in_sizes, int n_in,
                              void* d_out, int out_size, void* d_ws,
                              size_t ws_size, hipStream_t stream) {
  const float* z_re = (const float*)d_in[0];
  const float* z_im = (const float*)d_in[1];
  const float* canon = (const float*)d_in[2];
  float* out = (float*)d_out;
  float* ref = (float*)d_ws;  // 10 * 1024 * 4 B = 40 KiB

  ref_prep_kernel<<<N_CLS, 256, 0, stream>>>(canon, ref);

  const int nblk = NROWS / ROWS_PER_BLK;  // 2048
  swaptest_kernel<<<nblk, 64, 0, stream>>>(z_re, z_im, ref, out);
}